// Round 4
// baseline (208.929 us; speedup 1.0000x reference)
//
#include <hip/hip_runtime.h>
#include <stdint.h>

namespace {

constexpr int kB = 256;
constexpr int kV = 128000;
constexpr int kSplit = 8;                       // V-chunks per row
constexpr int kBlk = 256;
constexpr int kChunk = kV / kSplit;             // 16000, divisible by 8
constexpr int kElem = 8;                        // elements per lane per iter

struct Part { float val; int idx; };

// ---------------------------------------------------------------------------
// JAX threefry2x32, key = (0, 42); partitionable mode: bits[i] = o0 ^ o1 of
// threefry(x0 = hi32(i) = 0, x1 = i). Bit-exact vs reference (absmax = 0 in
// R0/R2/R3). 8-wide with NAMED SCALARS (no arrays -> no SROA/scratch risk)
// and sched_barrier(0) after every round/injection: R2/R3 showed the AMDGPU
// scheduler legally reorders independent chains chain-major and packs them
// into 32 VGPRs (ILP=1, latency-bound). The barriers pin round-major order:
// >=16 values live across every barrier, ILP=8 inside each 24-op window.
// ---------------------------------------------------------------------------

__global__ __launch_bounds__(kBlk, 2) void sampler_partial(
    const float* __restrict__ logits, const float* __restrict__ temps,
    Part* __restrict__ parts) {
  const int r = blockIdx.x / kSplit;
  const int g = blockIdx.x % kSplit;
  const float t = temps[r];
  const bool greedy = (t == 0.0f);
  const int start = g * kChunk;
  const int end = start + kChunk;
  const float* __restrict__ row = logits + (size_t)r * kV;

  float best = -__builtin_inff();
  int bi = 0;

  if (greedy) {
    // pure argmax of raw logits, first-occurrence tie-break (strict >)
    for (int v = start + (int)threadIdx.x * kElem; v + (kElem - 1) < end;
         v += kBlk * kElem) {
      float4 a = *reinterpret_cast<const float4*>(row + v);
      float4 b = *reinterpret_cast<const float4*>(row + v + 4);
      float la[8] = {a.x, a.y, a.z, a.w, b.x, b.y, b.z, b.w};
#pragma unroll
      for (int j = 0; j < 8; ++j) {
        if (la[j] > best) { best = la[j]; bi = v + j; }
      }
    }
  } else {
    constexpr uint32_t ks0 = 0u;
    constexpr uint32_t ks1 = 42u;
    constexpr uint32_t ks2 = 0x1BD11BDAu ^ ks0 ^ ks1;
    constexpr float kTiny = 1.17549435e-38f;   // FLT_MIN
    constexpr float kNegLn2 = -0.69314718055994530942f;
    constexpr float kNegLnLn2 = 0.36651292058166432701f;  // -ln(ln 2)

// rotl(x, r) == v_alignbit_b32(x, x, 32-r)  (single instruction, guaranteed)
#define ROTL_(x, rr) __builtin_amdgcn_alignbit((x), (x), 32u - (rr))
#define SB_ __builtin_amdgcn_sched_barrier(0)

#define TF_STEP(j, rr)                                                \
  x0_##j += x1_##j;                                                   \
  x1_##j = ROTL_(x1_##j, rr);                                         \
  x1_##j ^= x0_##j;
#define TF_R(rr)                                                      \
  TF_STEP(0, rr) TF_STEP(1, rr) TF_STEP(2, rr) TF_STEP(3, rr)         \
  TF_STEP(4, rr) TF_STEP(5, rr) TF_STEP(6, rr) TF_STEP(7, rr)         \
  SB_;
#define INJ_STEP(j, aa, bb)                                           \
  x0_##j += (aa);                                                     \
  x1_##j += (bb);
#define TF_INJ(aa, bb)                                                \
  INJ_STEP(0, aa, bb) INJ_STEP(1, aa, bb) INJ_STEP(2, aa, bb)         \
  INJ_STEP(3, aa, bb) INJ_STEP(4, aa, bb) INJ_STEP(5, aa, bb)         \
  INJ_STEP(6, aa, bb) INJ_STEP(7, aa, bb)                             \
  SB_;
#define ALL8(M) M(0) M(1) M(2) M(3) M(4) M(5) M(6) M(7)

#pragma clang loop unroll(disable)
    for (int v = start + (int)threadIdx.x * kElem; v + (kElem - 1) < end;
         v += kBlk * kElem) {
      // loads issued first; first use is ~600 pinned insts below -> the
      // vmcnt wait lands after the threefry body (natural prefetch).
      float4 a = *reinterpret_cast<const float4*>(row + v);
      float4 b = *reinterpret_cast<const float4*>(row + v + 4);

      const uint32_t base = (uint32_t)(r * kV + v) + ks1;  // flat idx < 2^25
#define DECL_X(j) uint32_t x0_##j = ks0; uint32_t x1_##j = base + (uint32_t)j;
      ALL8(DECL_X)
#undef DECL_X
      SB_;

      TF_R(13) TF_R(15) TF_R(26) TF_R(6)
      TF_INJ(ks1, ks2 + 1u)
      TF_R(17) TF_R(29) TF_R(16) TF_R(24)
      TF_INJ(ks2, ks0 + 2u)
      TF_R(13) TF_R(15) TF_R(26) TF_R(6)
      TF_INJ(ks0, ks1 + 3u)
      TF_R(17) TF_R(29) TF_R(16) TF_R(24)
      TF_INJ(ks1, ks2 + 4u)
      TF_R(13) TF_R(15) TF_R(26) TF_R(6)
      TF_INJ(ks2, ks0 + 5u)

      // gumbel, stage-major (each stage: 8 independent ops, then barrier).
      // f = bitcast(bits>>9 | 0x3f800000) - 1 exact; ref's max(tiny, f+tiny)
      // == fmaxf(f, tiny) bit-exactly. Same verified math as R0/R2/R3.
#define G_BITS(j) uint32_t bx_##j = x0_##j ^ x1_##j;
      ALL8(G_BITS) SB_;
#define G_F(j) float f_##j = __uint_as_float((bx_##j >> 9) | 0x3F800000u) - 1.0f;
      ALL8(G_F) SB_;
#define G_U(j) float u_##j = fmaxf(f_##j, kTiny);
      ALL8(G_U) SB_;
#define G_Z(j) float z_##j = __builtin_amdgcn_logf(u_##j);
      ALL8(G_Z) SB_;
#define G_W(j) float w_##j = __builtin_amdgcn_logf(-z_##j);
      ALL8(G_W) SB_;
#define G_G(j) float g_##j = fmaf(kNegLn2, w_##j, kNegLnLn2);
      ALL8(G_G) SB_;

      const float la_0 = a.x, la_1 = a.y, la_2 = a.z, la_3 = a.w;
      const float la_4 = b.x, la_5 = b.y, la_6 = b.z, la_7 = b.w;
      // argmax(la/t + g) == argmax(la + t*g) for t > 0 (monotonic).
      // ascending j + strict > keeps first occurrence.
#define UPD(j)                                                        \
  {                                                                   \
    float key_##j = fmaf(t, g_##j, la_##j);                           \
    if (key_##j > best) { best = key_##j; bi = v + j; }               \
  }
      ALL8(UPD)
#undef UPD
#undef G_G
#undef G_W
#undef G_Z
#undef G_U
#undef G_F
#undef G_BITS
    }
#undef ALL8
#undef TF_INJ
#undef INJ_STEP
#undef TF_R
#undef TF_STEP
#undef SB_
#undef ROTL_
  }

  __shared__ float sv[kBlk];
  __shared__ int si[kBlk];
  sv[threadIdx.x] = best;
  si[threadIdx.x] = bi;
  __syncthreads();
  for (int s = kBlk / 2; s > 0; s >>= 1) {
    if ((int)threadIdx.x < s) {
      float ov = sv[threadIdx.x + s]; int oi = si[threadIdx.x + s];
      float mv = sv[threadIdx.x];     int mi = si[threadIdx.x];
      if (ov > mv || (ov == mv && oi < mi)) {
        sv[threadIdx.x] = ov; si[threadIdx.x] = oi;
      }
    }
    __syncthreads();
  }
  if (threadIdx.x == 0) {
    parts[r * kSplit + g].val = sv[0];
    parts[r * kSplit + g].idx = si[0];
  }
}

__global__ __launch_bounds__(kB) void sampler_final(
    const Part* __restrict__ parts, int* __restrict__ out) {
  const int r = threadIdx.x;
  if (r < kB) {
    float bv = -__builtin_inff();
    int bi = 0;
    for (int g = 0; g < kSplit; ++g) {
      Part p = parts[r * kSplit + g];
      if (p.val > bv || (p.val == bv && p.idx < bi)) { bv = p.val; bi = p.idx; }
    }
    out[r] = bi;
  }
}

}  // namespace

extern "C" void kernel_launch(void* const* d_in, const int* in_sizes, int n_in,
                              void* d_out, int out_size, void* d_ws, size_t ws_size,
                              hipStream_t stream) {
  const float* logits = (const float*)d_in[0];
  const float* temps = (const float*)d_in[1];
  int* out = (int*)d_out;
  Part* parts = (Part*)d_ws;  // kB * kSplit * 8 B = 16 KiB

  sampler_partial<<<dim3(kB * kSplit), dim3(kBlk), 0, stream>>>(logits, temps, parts);
  sampler_final<<<dim3(1), dim3(kB), 0, stream>>>(parts, out);
}

// Round 5
// 199.928 us; speedup vs baseline: 1.0450x; 1.0450x over previous
//
#include <hip/hip_runtime.h>
#include <stdint.h>

namespace {

constexpr int kB = 256;
constexpr int kV = 128000;
constexpr int kSplit = 8;                       // V-chunks per row
constexpr int kBlk = 256;
constexpr int kChunk = kV / kSplit;             // 16000, divisible by 8
constexpr int kElem = 8;                        // elements per lane per iter

struct Part { float val; int idx; };

// ---------------------------------------------------------------------------
// JAX threefry2x32, key = (0, 42); partitionable mode: bits[i] = o0 ^ o1 of
// threefry(x0 = hi32(i) = 0, x1 = i). Bit-exact vs reference (absmax = 0 in
// R0/R2/R3/R4).
//
// R2/R3/R4 lesson: every source-level ILP structure (arrays, named scalars,
// sched_barrier(0)) was legally re-serialized chain-major by IR-level sinking
// (VGPR_Count 24-32, ILP=1, ~78 us plateau). This build hand-emits the
// threefry core as ONE atomic asm blob per 4 elements, stage-major within
// each round (add x4, alignbit x4, xor x4): dependent ops are >=4 issue slots
// (>=8 cyc) apart vs ~4 cyc VALU dep latency -> stall-free by construction,
// and no compiler pass can reorder inside the blob.
//
// Constants: ks0=0, ks1=42, ks2=0x1BD11BDA^0^42=0x1BD11BF0.
// Rotations 13,15,26,6 / 17,29,16,24 -> alignbit shifts 32-r:
// 19,17,6,26 / 15,3,16,8. Injections after each 4-round group:
//   (+42, +0x1BD11BF1) (+0x1BD11BF0, +2) (+0, +45) (+42, +0x1BD11BF4)
//   (+0x1BD11BF0, +5);  the +0 add is omitted (bit-exact no-op).
// ---------------------------------------------------------------------------

// one round, 4 chains, stage-major; S = 32 - rotation (string literal)
#define TFR(S) \
  "v_add_u32 %[x00], %[x00], %[x10]\n\t" \
  "v_add_u32 %[x01], %[x01], %[x11]\n\t" \
  "v_add_u32 %[x02], %[x02], %[x12]\n\t" \
  "v_add_u32 %[x03], %[x03], %[x13]\n\t" \
  "v_alignbit_b32 %[x10], %[x10], %[x10], " S "\n\t" \
  "v_alignbit_b32 %[x11], %[x11], %[x11], " S "\n\t" \
  "v_alignbit_b32 %[x12], %[x12], %[x12], " S "\n\t" \
  "v_alignbit_b32 %[x13], %[x13], %[x13], " S "\n\t" \
  "v_xor_b32 %[x10], %[x10], %[x00]\n\t" \
  "v_xor_b32 %[x11], %[x11], %[x01]\n\t" \
  "v_xor_b32 %[x12], %[x12], %[x02]\n\t" \
  "v_xor_b32 %[x13], %[x13], %[x03]\n\t"

// key injections (literal goes in src0 of v_add_u32; vsrc1 is the VGPR)
#define TFI_A(A) \
  "v_add_u32 %[x00], " A ", %[x00]\n\t" \
  "v_add_u32 %[x01], " A ", %[x01]\n\t" \
  "v_add_u32 %[x02], " A ", %[x02]\n\t" \
  "v_add_u32 %[x03], " A ", %[x03]\n\t"
#define TFI_B(Bc) \
  "v_add_u32 %[x10], " Bc ", %[x10]\n\t" \
  "v_add_u32 %[x11], " Bc ", %[x11]\n\t" \
  "v_add_u32 %[x12], " Bc ", %[x12]\n\t" \
  "v_add_u32 %[x13], " Bc ", %[x13]\n\t"

// bits[0..3] for counters base+0..base+3
__device__ __forceinline__ void threefry4(uint32_t base, uint32_t* bits) {
  uint32_t x00, x01, x02, x03, x10, x11, x12, x13;
  asm(
      // x1_j = base + (42 + j)   (42..45 are inline constants, free)
      "v_add_u32 %[x10], 42, %[base]\n\t"
      "v_add_u32 %[x11], 43, %[base]\n\t"
      "v_add_u32 %[x12], 44, %[base]\n\t"
      "v_add_u32 %[x13], 45, %[base]\n\t"
      "v_mov_b32 %[x00], 0\n\t"
      "v_mov_b32 %[x01], 0\n\t"
      "v_mov_b32 %[x02], 0\n\t"
      "v_mov_b32 %[x03], 0\n\t"
      TFR("19") TFR("17") TFR("6") TFR("26")
      TFI_A("42") TFI_B("0x1BD11BF1")
      TFR("15") TFR("3") TFR("16") TFR("8")
      TFI_A("0x1BD11BF0") TFI_B("2")
      TFR("19") TFR("17") TFR("6") TFR("26")
      TFI_B("45")                                   // x0 += 0 omitted
      TFR("15") TFR("3") TFR("16") TFR("8")
      TFI_A("42") TFI_B("0x1BD11BF4")
      TFR("19") TFR("17") TFR("6") TFR("26")
      TFI_A("0x1BD11BF0") TFI_B("5")
      : [x00] "=&v"(x00), [x01] "=&v"(x01), [x02] "=&v"(x02),
        [x03] "=&v"(x03), [x10] "=&v"(x10), [x11] "=&v"(x11),
        [x12] "=&v"(x12), [x13] "=&v"(x13)
      : [base] "v"(base));
  bits[0] = x00 ^ x10;
  bits[1] = x01 ^ x11;
  bits[2] = x02 ^ x12;
  bits[3] = x03 ^ x13;
}

#undef TFR
#undef TFI_A
#undef TFI_B

// gumbel = -ln(-ln(u)).
// f = bitcast(bits>>9 | 0x3f800000) - 1 exact (Sterbenz); ref's
// max(tiny, f + tiny) == fmaxf(f, tiny) bit-exactly.
// -ln(-ln u) = -ln2*log2(-log2 u) - ln(ln2): negate folds into v_log_f32's
// input modifier, scale+offset is one fma. Same verified math as R0-R4
// (absmax = 0; ~5e-7 abs err in g vs O(1) top-2 gumbel gaps).
__device__ __forceinline__ float gumbel_from_bits(uint32_t bits) {
  constexpr float kTiny = 1.17549435e-38f;   // FLT_MIN
  constexpr float kNegLn2 = -0.69314718055994530942f;
  constexpr float kNegLnLn2 = 0.36651292058166432701f;  // -ln(ln 2)
  float f = __uint_as_float((bits >> 9) | 0x3F800000u) - 1.0f;
  float u = fmaxf(f, kTiny);
  float z = __builtin_amdgcn_logf(u);         // log2(u) < 0
  float w = __builtin_amdgcn_logf(-z);        // log2(-log2(u))
  return fmaf(kNegLn2, w, kNegLnLn2);
}

__global__ __launch_bounds__(kBlk, 2) void sampler_partial(
    const float* __restrict__ logits, const float* __restrict__ temps,
    Part* __restrict__ parts) {
  const int r = blockIdx.x / kSplit;
  const int g = blockIdx.x % kSplit;
  const float t = temps[r];
  const bool greedy = (t == 0.0f);
  const int start = g * kChunk;
  const int end = start + kChunk;
  const float* __restrict__ row = logits + (size_t)r * kV;

  float best = -__builtin_inff();
  int bi = 0;

  if (greedy) {
    // pure argmax of raw logits, first-occurrence tie-break (strict >)
    for (int v = start + (int)threadIdx.x * kElem; v + (kElem - 1) < end;
         v += kBlk * kElem) {
      float4 a = *reinterpret_cast<const float4*>(row + v);
      float4 b = *reinterpret_cast<const float4*>(row + v + 4);
      float la[8] = {a.x, a.y, a.z, a.w, b.x, b.y, b.z, b.w};
#pragma unroll
      for (int j = 0; j < 8; ++j) {
        if (la[j] > best) { best = la[j]; bi = v + j; }
      }
    }
  } else {
    // argmax(la/t + g) == argmax(la + t*g) for t > 0 (monotonic).
    // Loads issue first; first use is ~600 asm insts later -> vmcnt wait
    // lands after the threefry work (natural prefetch).
#pragma clang loop unroll(disable)
    for (int v = start + (int)threadIdx.x * kElem; v + (kElem - 1) < end;
         v += kBlk * kElem) {
      float4 a = *reinterpret_cast<const float4*>(row + v);
      float4 b = *reinterpret_cast<const float4*>(row + v + 4);

      const uint32_t flat = (uint32_t)(r * kV + v);  // < 2^25
      uint32_t bits[8];
      threefry4(flat, bits);
      threefry4(flat + 4u, bits + 4);

      float la[8] = {a.x, a.y, a.z, a.w, b.x, b.y, b.z, b.w};
      // ascending j + strict > keeps first occurrence on exact ties
#pragma unroll
      for (int j = 0; j < 8; ++j) {
        float key = fmaf(t, gumbel_from_bits(bits[j]), la[j]);
        if (key > best) { best = key; bi = v + j; }
      }
    }
  }

  __shared__ float sv[kBlk];
  __shared__ int si[kBlk];
  sv[threadIdx.x] = best;
  si[threadIdx.x] = bi;
  __syncthreads();
  for (int s = kBlk / 2; s > 0; s >>= 1) {
    if ((int)threadIdx.x < s) {
      float ov = sv[threadIdx.x + s]; int oi = si[threadIdx.x + s];
      float mv = sv[threadIdx.x];     int mi = si[threadIdx.x];
      if (ov > mv || (ov == mv && oi < mi)) {
        sv[threadIdx.x] = ov; si[threadIdx.x] = oi;
      }
    }
    __syncthreads();
  }
  if (threadIdx.x == 0) {
    parts[r * kSplit + g].val = sv[0];
    parts[r * kSplit + g].idx = si[0];
  }
}

__global__ __launch_bounds__(kB) void sampler_final(
    const Part* __restrict__ parts, int* __restrict__ out) {
  const int r = threadIdx.x;
  if (r < kB) {
    float bv = -__builtin_inff();
    int bi = 0;
    for (int g = 0; g < kSplit; ++g) {
      Part p = parts[r * kSplit + g];
      if (p.val > bv || (p.val == bv && p.idx < bi)) { bv = p.val; bi = p.idx; }
    }
    out[r] = bi;
  }
}

}  // namespace

extern "C" void kernel_launch(void* const* d_in, const int* in_sizes, int n_in,
                              void* d_out, int out_size, void* d_ws, size_t ws_size,
                              hipStream_t stream) {
  const float* logits = (const float*)d_in[0];
  const float* temps = (const float*)d_in[1];
  int* out = (int*)d_out;
  Part* parts = (Part*)d_ws;  // kB * kSplit * 8 B = 16 KiB

  sampler_partial<<<dim3(kB * kSplit), dim3(kBlk), 0, stream>>>(logits, temps, parts);
  sampler_final<<<dim3(1), dim3(kB), 0, stream>>>(parts, out);
}